// Round 2
// baseline (737.681 us; speedup 1.0000x reference)
//
#include <hip/hip_runtime.h>
#include <hip/hip_bf16.h>

#define HID 1024
#define BATCH 32
#define SEQ 2048
#define MROWS (BATCH*SEQ)   // 65536

typedef __bf16 bf16x8 __attribute__((ext_vector_type(8)));
typedef float f32x4 __attribute__((ext_vector_type(4)));

__device__ __forceinline__ unsigned short f2bf(float f) {
  unsigned int x = __float_as_uint(f);
  x += 0x7FFFu + ((x >> 16) & 1u);   // RNE
  return (unsigned short)(x >> 16);
}

// ---------------------------------------------------------------------------
// convert_past: f32 past (256 MB) -> bf16 Abf (128 MB). Memory-bound stream.
// grid = 2048, block = 256, grid-stride; compiler lowers casts to HW cvt.
// ---------------------------------------------------------------------------
__global__ __launch_bounds__(256) void convert_past(
    const float* __restrict__ past, unsigned short* __restrict__ Abf)
{
  const long n8 = (long)MROWS * HID / 8;          // 8 Mi chunks of 8 elems
  const long stride = (long)gridDim.x * 256;
  for (long i = (long)blockIdx.x * 256 + threadIdx.x; i < n8; i += stride) {
    float4 a = ((const float4*)past)[2 * i];
    float4 b = ((const float4*)past)[2 * i + 1];
    bf16x8 o;
    o[0] = (__bf16)a.x; o[1] = (__bf16)a.y; o[2] = (__bf16)a.z; o[3] = (__bf16)a.w;
    o[4] = (__bf16)b.x; o[5] = (__bf16)b.y; o[6] = (__bf16)b.z; o[7] = (__bf16)b.w;
    ((bf16x8*)Abf)[i] = o;
  }
}

// ---------------------------------------------------------------------------
// prep: convert Wp (=W_proj[:, :1024]) to bf16 row-major [h][d]; compute
// c[b,h] = dot(current[b,:], Wc[h,:]) + b_proj[h] in fp32.
// grid = 1024 (one block per h), block = 256.
// ---------------------------------------------------------------------------
__global__ __launch_bounds__(256) void prep_kernel(
    const float* __restrict__ cur, const float* __restrict__ Wproj,
    const float* __restrict__ bproj, unsigned short* __restrict__ Bbf,
    float* __restrict__ c_ws)
{
  int h = blockIdx.x, t = threadIdx.x;
  float4 v = ((const float4*)(Wproj + (long)h * 2048))[t];
  ushort4 u; u.x = f2bf(v.x); u.y = f2bf(v.y); u.z = f2bf(v.z); u.w = f2bf(v.w);
  ((ushort4*)(Bbf + (long)h * 1024))[t] = u;

  __shared__ float wc[HID];
  float4 w4 = ((const float4*)(Wproj + (long)h * 2048 + 1024))[t];
  ((float4*)wc)[t] = w4;
  __syncthreads();

  int wv = t >> 6, l = t & 63;
  float bp = bproj[h];
  for (int i = 0; i < 8; ++i) {
    int b = wv * 8 + i;
    const float* cb = cur + b * HID;
    float s = 0.f;
    #pragma unroll
    for (int j = 0; j < 16; ++j) { int d = l + j * 64; s += cb[d] * wc[d]; }
    #pragma unroll
    for (int m = 1; m < 64; m <<= 1) s += __shfl_xor(s, m, 64);
    if (l == 0) c_ws[b * HID + h] = s + bp;
  }
}

#define BM 128
#define BN 128
#define BK 64

// ---------------------------------------------------------------------------
// FAST score GEMM (m97 structure): A = bf16 past (pre-converted), B = bf16 Wp.
// Both staged via global_load_lds width 16, linear LDS, 2-barrier loop.
// C[m,n] = sum_k A[m,k]*B[n,k]; epilogue: scores[m] += sum_n w[n]*tanh(C+c).
// grid = 4096 (XCD-swizzled), block = 256.
// ---------------------------------------------------------------------------
__global__ __launch_bounds__(256) void score_gemm_bf(
    const unsigned short* __restrict__ Abf, const unsigned short* __restrict__ Bbf,
    const float* __restrict__ c_ws, const float* __restrict__ wsc,
    float* __restrict__ scores)
{
  __shared__ unsigned short As[BM * BK];  // 16 KB, linear
  __shared__ unsigned short Bs[BN * BK];  // 16 KB, linear

  int bid = blockIdx.x;
  int wg = (bid & 7) * 512 + (bid >> 3);   // 512 consecutive wg per XCD
  int mt = wg >> 3, nt = wg & 7;
  long row0 = (long)mt * BM;
  int n0 = nt * BN;
  int b = mt >> 4;

  int t = threadIdx.x;
  int w = t >> 6, lane = t & 63;
  int wr = w >> 1, wcn = w & 1;
  int la = lane & 15, lb = lane >> 4;

  f32x4 acc[4][4] = {};

  for (int kt = 0; kt < HID / BK; ++kt) {
    int k0 = kt * BK;
    __syncthreads();   // previous tile's ds_reads done before DMA overwrites
    #pragma unroll
    for (int i = 0; i < 4; ++i) {
      int c = t + 256 * i;                 // 0..1023: 16B chunk index
      int r = c >> 3, fc = (c & 7) * 8;    // 8 chunks/row, fc in bf16 elems
      const unsigned short* srcA = Abf + (row0 + r) * 1024 + k0 + fc;
      __builtin_amdgcn_global_load_lds(
          (const __attribute__((address_space(1))) void*)srcA,
          (__attribute__((address_space(3))) void*)((char*)As + c * 16), 16, 0, 0);
      const unsigned short* srcB = Bbf + (long)(n0 + r) * 1024 + k0 + fc;
      __builtin_amdgcn_global_load_lds(
          (const __attribute__((address_space(1))) void*)srcB,
          (__attribute__((address_space(3))) void*)((char*)Bs + c * 16), 16, 0, 0);
    }
    __syncthreads();   // vmcnt drained by compiler before barrier
    #pragma unroll
    for (int kk = 0; kk < 2; ++kk) {
      bf16x8 af[4], bfv[4];
      #pragma unroll
      for (int m = 0; m < 4; ++m) {
        int r = wr * 64 + m * 16 + la;
        af[m] = *(const bf16x8*)((const char*)As + r * 128 + kk * 64 + lb * 16);
      }
      #pragma unroll
      for (int n = 0; n < 4; ++n) {
        int r = wcn * 64 + n * 16 + la;
        bfv[n] = *(const bf16x8*)((const char*)Bs + r * 128 + kk * 64 + lb * 16);
      }
      #pragma unroll
      for (int m = 0; m < 4; ++m)
        #pragma unroll
        for (int n = 0; n < 4; ++n)
          acc[m][n] = __builtin_amdgcn_mfma_f32_16x16x32_bf16(
              af[m], bfv[n], acc[m][n], 0, 0, 0);
    }
  }

  const float* crow = c_ws + b * HID;
  float ch[4], wv4[4];
  #pragma unroll
  for (int n = 0; n < 4; ++n) {
    int h = n0 + wcn * 64 + n * 16 + la;
    ch[n] = crow[h];
    wv4[n] = wsc[h];
  }
  #pragma unroll
  for (int m = 0; m < 4; ++m) {
    #pragma unroll
    for (int j = 0; j < 4; ++j) {
      float rs = 0.f;
      #pragma unroll
      for (int n = 0; n < 4; ++n)
        rs += wv4[n] * tanhf(acc[m][n][j] + ch[n]);
      rs += __shfl_xor(rs, 1, 64);
      rs += __shfl_xor(rs, 2, 64);
      rs += __shfl_xor(rs, 4, 64);
      rs += __shfl_xor(rs, 8, 64);
      if (la == 0) {
        long grow = row0 + wr * 64 + m * 16 + lb * 4 + j;
        atomicAdd(scores + grow, rs);
      }
    }
  }
}

// ---------------------------------------------------------------------------
// FALLBACK score GEMM (on-the-fly f32->bf16 A staging) — used if ws too small.
// ---------------------------------------------------------------------------
__global__ __launch_bounds__(256) void score_gemm(
    const float* __restrict__ past, const unsigned short* __restrict__ Bbf,
    const float* __restrict__ c_ws, const float* __restrict__ wsc,
    float* __restrict__ scores)
{
  __shared__ unsigned short As[BM * BK];
  __shared__ unsigned short Bs[BN * BK];

  int bid = blockIdx.x;
  int wg = (bid & 7) * 512 + (bid >> 3);
  int mt = wg >> 3, nt = wg & 7;
  long row0 = (long)mt * BM;
  int n0 = nt * BN;
  int b = mt >> 4;

  int t = threadIdx.x;
  int w = t >> 6, lane = t & 63;
  int wr = w >> 1, wcn = w & 1;
  int la = lane & 15, lb = lane >> 4;

  f32x4 acc[4][4] = {};

  for (int kt = 0; kt < HID / BK; ++kt) {
    int k0 = kt * BK;
    float4 av[8];
    #pragma unroll
    for (int i = 0; i < 8; ++i) {
      int c = t + 256 * i;
      int r = c >> 4, fc = c & 15;
      av[i] = ((const float4*)(past + (row0 + r) * 1024 + k0))[fc];
    }
    __syncthreads();
    #pragma unroll
    for (int i = 0; i < 8; ++i) {
      int c = t + 256 * i;
      int r = c >> 4, fc = c & 15;
      int off = (r * 128 + fc * 8) ^ ((r & 7) << 4);
      ushort4 uu; uu.x = f2bf(av[i].x); uu.y = f2bf(av[i].y);
      uu.z = f2bf(av[i].z); uu.w = f2bf(av[i].w);
      *(ushort4*)((char*)As + off) = uu;
    }
    #pragma unroll
    for (int i = 0; i < 4; ++i) {
      int o = (t + 256 * i) * 16;
      int uoff = o ^ (((o >> 7) & 7) << 4);
      int n = uoff >> 7, inb = uoff & 127;
      const unsigned short* src = Bbf + (long)(n0 + n) * 1024 + k0 + (inb >> 1);
      __builtin_amdgcn_global_load_lds(
          (const __attribute__((address_space(1))) void*)src,
          (__attribute__((address_space(3))) void*)((char*)Bs + o), 16, 0, 0);
    }
    __syncthreads();
    #pragma unroll
    for (int kk = 0; kk < 2; ++kk) {
      bf16x8 af[4], bfv[4];
      #pragma unroll
      for (int m = 0; m < 4; ++m) {
        int r = wr * 64 + m * 16 + la;
        int off = (r * 128 + kk * 64 + lb * 16) ^ ((r & 7) << 4);
        af[m] = *(const bf16x8*)((const char*)As + off);
      }
      #pragma unroll
      for (int n = 0; n < 4; ++n) {
        int r = wcn * 64 + n * 16 + la;
        int off = (r * 128 + kk * 64 + lb * 16) ^ ((r & 7) << 4);
        bfv[n] = *(const bf16x8*)((const char*)Bs + off);
      }
      #pragma unroll
      for (int m = 0; m < 4; ++m)
        #pragma unroll
        for (int n = 0; n < 4; ++n)
          acc[m][n] = __builtin_amdgcn_mfma_f32_16x16x32_bf16(
              af[m], bfv[n], acc[m][n], 0, 0, 0);
    }
  }

  const float* crow = c_ws + b * HID;
  float ch[4], wv4[4];
  #pragma unroll
  for (int n = 0; n < 4; ++n) {
    int h = n0 + wcn * 64 + n * 16 + la;
    ch[n] = crow[h];
    wv4[n] = wsc[h];
  }
  #pragma unroll
  for (int m = 0; m < 4; ++m) {
    #pragma unroll
    for (int j = 0; j < 4; ++j) {
      float rs = 0.f;
      #pragma unroll
      for (int n = 0; n < 4; ++n)
        rs += wv4[n] * tanhf(acc[m][n][j] + ch[n]);
      rs += __shfl_xor(rs, 1, 64);
      rs += __shfl_xor(rs, 2, 64);
      rs += __shfl_xor(rs, 4, 64);
      rs += __shfl_xor(rs, 8, 64);
      if (la == 0) {
        long grow = row0 + wr * 64 + m * 16 + lb * 4 + j;
        atomicAdd(scores + grow, rs);
      }
    }
  }
}

// ---------------------------------------------------------------------------
// softmax over s (in place). grid=32, block=256.
// ---------------------------------------------------------------------------
__global__ __launch_bounds__(256) void softmax_kernel(float* __restrict__ sc)
{
  int b = blockIdx.x, t = threadIdx.x;
  float* row = sc + (long)b * SEQ;
  float v[8]; float mx = -1e30f;
  #pragma unroll
  for (int j = 0; j < 8; ++j) { v[j] = row[t + j * 256]; mx = fmaxf(mx, v[j]); }
  #pragma unroll
  for (int m = 1; m < 64; m <<= 1) mx = fmaxf(mx, __shfl_xor(mx, m, 64));
  __shared__ float rmax[4], rsum[4];
  if ((t & 63) == 0) rmax[t >> 6] = mx;
  __syncthreads();
  mx = fmaxf(fmaxf(rmax[0], rmax[1]), fmaxf(rmax[2], rmax[3]));
  float s = 0.f;
  #pragma unroll
  for (int j = 0; j < 8; ++j) { v[j] = expf(v[j] - mx); s += v[j]; }
  #pragma unroll
  for (int m = 1; m < 64; m <<= 1) s += __shfl_xor(s, m, 64);
  if ((t & 63) == 0) rsum[t >> 6] = s;
  __syncthreads();
  float inv = 1.f / (rsum[0] + rsum[1] + rsum[2] + rsum[3]);
  #pragma unroll
  for (int j = 0; j < 8; ++j) row[t + j * 256] = v[j] * inv;
}

// ---------------------------------------------------------------------------
// attended stage 1: partial[b*C+sc][d] = sum_{s in chunk} attn[b,s]*past[b,s,d]
// rows-per-chunk = SEQ>>cshift; grid = 32<<cshift, block = 256.
// ---------------------------------------------------------------------------
__global__ __launch_bounds__(256) void attend_partial(
    const float* __restrict__ past, const float* __restrict__ attn,
    float* __restrict__ partial, int cshift)
{
  int blk = blockIdx.x;
  int b = blk >> cshift, scn = blk & ((1 << cshift) - 1);
  int rows = SEQ >> cshift;
  int t = threadIdx.x;
  int s0 = scn * rows;
  __shared__ float aw[128];
  if (t < rows) aw[t] = attn[(long)b * SEQ + s0 + t];
  __syncthreads();
  const float4* pp = (const float4*)(past + ((long)(b * SEQ + s0)) * HID);
  float ax = 0.f, ay = 0.f, az = 0.f, awv = 0.f;
  #pragma unroll 4
  for (int s = 0; s < rows; ++s) {
    float wgt = aw[s];
    float4 v = pp[s * 256 + t];
    ax += wgt * v.x; ay += wgt * v.y; az += wgt * v.z; awv += wgt * v.w;
  }
  float4 o; o.x = ax; o.y = ay; o.z = az; o.w = awv;
  ((float4*)(partial + (long)blk * HID))[t] = o;
}

// attended stage 2: out[b,d] = sum_sc partial[b*C+sc][d]. grid=128, block=256.
__global__ __launch_bounds__(256) void attend_reduce(
    const float* __restrict__ partial, float* __restrict__ out, int nchunks)
{
  int blk = blockIdx.x;
  int b = blk >> 2, d = (blk & 3) * 256 + threadIdx.x;
  float s = 0.f;
  for (int sc = 0; sc < nchunks; ++sc)
    s += partial[(long)(b * nchunks + sc) * HID + d];
  out[(long)b * HID + d] = s;
}

// ---------------------------------------------------------------------------
extern "C" void kernel_launch(void* const* d_in, const int* in_sizes, int n_in,
                              void* d_out, int out_size, void* d_ws, size_t ws_size,
                              hipStream_t stream)
{
  const float* cur   = (const float*)d_in[0];  // (32,1024)
  const float* past  = (const float*)d_in[1];  // (32,2048,1024)
  const float* Wproj = (const float*)d_in[2];  // (1024,2048)
  const float* bproj = (const float*)d_in[3];  // (1024,)
  const float* wsc   = (const float*)d_in[4];  // (1024,)

  float* out      = (float*)d_out;
  float* attended = out;            // 32768 floats
  float* scores   = out + 32768;    // 65536 floats (scores -> attn in place)

  char* ws = (char*)d_ws;
  float*          c_ws    = (float*)ws;                              // 128 KB
  unsigned short* Bbf     = (unsigned short*)(ws + (128 << 10));     // 2 MB
  float*          partial = (float*)(ws + (128 << 10) + (2 << 20));  // <= 8 MB
  unsigned short* Abf     = (unsigned short*)(ws + (128 << 10) + (10 << 20)); // 128 MB

  const size_t NEED_FAST = (size_t)(128 << 10) + (10 << 20) + ((size_t)128 << 20);
  const bool fast = ws_size >= NEED_FAST;

  hipMemsetAsync(scores, 0, (size_t)BATCH * SEQ * sizeof(float), stream);
  prep_kernel<<<1024, 256, 0, stream>>>(cur, Wproj, bproj, Bbf, c_ws);
  if (fast) {
    convert_past<<<2048, 256, 0, stream>>>(past, Abf);
    score_gemm_bf<<<4096, 256, 0, stream>>>(Abf, Bbf, c_ws, wsc, scores);
  } else {
    score_gemm<<<4096, 256, 0, stream>>>(past, Bbf, c_ws, wsc, scores);
  }
  softmax_kernel<<<BATCH, 256, 0, stream>>>(scores);
  if (fast) {
    attend_partial<<<32 * 64, 256, 0, stream>>>(past, scores, partial, 6); // 32 rows/chunk
    attend_reduce<<<128, 256, 0, stream>>>(partial, attended, 64);
  } else {
    attend_partial<<<32 * 16, 256, 0, stream>>>(past, scores, partial, 4); // 128 rows/chunk
    attend_reduce<<<128, 256, 0, stream>>>(partial, attended, 16);
  }
}

// Round 4
// 698.407 us; speedup vs baseline: 1.0562x; 1.0562x over previous
//
#include <hip/hip_runtime.h>
#include <hip/hip_bf16.h>

#define HID 1024
#define BATCH 32
#define SEQ 2048

typedef __bf16 bf16x8 __attribute__((ext_vector_type(8)));
typedef float f32x4 __attribute__((ext_vector_type(4)));

__device__ __forceinline__ unsigned short f2bf(float f) {
  unsigned int x = __float_as_uint(f);
  x += 0x7FFFu + ((x >> 16) & 1u);   // RNE
  return (unsigned short)(x >> 16);
}

// ---------------------------------------------------------------------------
// prep: convert Wp (=W_proj[:, :1024]) to bf16 row-major [h][d]; compute
// c[b,h] = dot(current[b,:], Wc[h,:]) + b_proj[h] in fp32.
// grid = 1024 (one block per h), block = 256.
// ---------------------------------------------------------------------------
__global__ __launch_bounds__(256) void prep_kernel(
    const float* __restrict__ cur, const float* __restrict__ Wproj,
    const float* __restrict__ bproj, unsigned short* __restrict__ Bbf,
    float* __restrict__ c_ws)
{
  int h = blockIdx.x, t = threadIdx.x;
  float4 v = ((const float4*)(Wproj + (long)h * 2048))[t];
  ushort4 u; u.x = f2bf(v.x); u.y = f2bf(v.y); u.z = f2bf(v.z); u.w = f2bf(v.w);
  ((ushort4*)(Bbf + (long)h * 1024))[t] = u;

  __shared__ float wc[HID];
  float4 w4 = ((const float4*)(Wproj + (long)h * 2048 + 1024))[t];
  ((float4*)wc)[t] = w4;
  __syncthreads();

  int wv = t >> 6, l = t & 63;
  float bp = bproj[h];
  for (int i = 0; i < 8; ++i) {
    int b = wv * 8 + i;
    const float* cb = cur + b * HID;
    float s = 0.f;
    #pragma unroll
    for (int j = 0; j < 16; ++j) { int d = l + j * 64; s += cb[d] * wc[d]; }
    #pragma unroll
    for (int m = 1; m < 64; m <<= 1) s += __shfl_xor(s, m, 64);
    if (l == 0) c_ws[b * HID + h] = s + bp;
  }
}

#define BM 128
#define BN 128
#define BK 64

// ---------------------------------------------------------------------------
// Fused score GEMM, double-buffered 2-phase pipeline:
//   C[m,n] = sum_k past[m,k]*Wp[n,k]   (A: f32->bf16 reg-staged, swizzled LDS;
//                                        B: bf16 via global_load_lds,
//                                        inverse-permuted source + swz read)
//   epilogue: scores[m] += sum_n w[n]*tanh(C[m,n] + c[b,n])
// grid = 4096 (XCD-swizzled), block = 256, LDS = 64 KB (2 blocks/CU).
// Loop: issue loads(t+1) -> compute(t) -> write A(t+1) -> ONE barrier.
// Safe: at iter kt all waves read only buf (kt&1); writes go to the other
// buffer, whose readers finished before the barrier ending iter kt-1.
// ---------------------------------------------------------------------------
__global__ __launch_bounds__(256, 2) void score_gemm(
    const float* __restrict__ past, const unsigned short* __restrict__ Bbf,
    const float* __restrict__ c_ws, const float* __restrict__ wsc,
    float* __restrict__ scores)
{
  __shared__ unsigned short As[2][BM * BK];  // 2 x 16 KB, XOR-swizzled
  __shared__ unsigned short Bs[2][BN * BK];  // 2 x 16 KB, XOR-swizzled

  int bid = blockIdx.x;
  int wg = (bid & 7) * 512 + (bid >> 3);   // 512 consecutive wg per XCD
  int mt = wg >> 3, nt = wg & 7;
  long row0 = (long)mt * BM;
  int n0 = nt * BN;
  int b = mt >> 4;

  int t = threadIdx.x;
  int w = t >> 6, lane = t & 63;
  int wr = w >> 1, wcn = w & 1;
  int la = lane & 15, lb = lane >> 4;

  // per-thread staging geometry (constant over K-loop)
  const float* aptr[4];
  const unsigned short* bptr[4];
  int awoff[4], bdoff[4];
  #pragma unroll
  for (int i = 0; i < 4; ++i) {
    int c = t + 256 * i;                   // 0..1023: one 16B chunk
    int r = c >> 3, q = c & 7;             // A: row r, 8-elem chunk q
    aptr[i] = past + (row0 + r) * 1024 + q * 8;
    awoff[i] = (r * 128 + q * 16) ^ ((r & 7) << 4);
    int o = c * 16;                        // B: linear LDS byte offset
    int uoff = o ^ (((o >> 7) & 7) << 4);  // involution -> source permute
    int n = uoff >> 7, inb = uoff & 127;
    bptr[i] = Bbf + (long)(n0 + n) * 1024 + (inb >> 1);
    bdoff[i] = o;
  }

  f32x4 acc[4][4] = {};
  float4 areg[4][2];

  auto LOADA = [&](int kt) {
    #pragma unroll
    for (int i = 0; i < 4; ++i) {
      const float* p = aptr[i] + kt * BK;
      areg[i][0] = *(const float4*)p;
      areg[i][1] = *(const float4*)(p + 4);
    }
  };
  auto DMAB = [&](int kt, int buf) {
    #pragma unroll
    for (int i = 0; i < 4; ++i)
      __builtin_amdgcn_global_load_lds(
          (const __attribute__((address_space(1))) void*)(bptr[i] + kt * BK),
          (__attribute__((address_space(3))) void*)((char*)Bs[buf] + bdoff[i]),
          16, 0, 0);
  };
  auto WRITEA = [&](int buf) {
    #pragma unroll
    for (int i = 0; i < 4; ++i) {
      bf16x8 o;
      o[0] = (__bf16)areg[i][0].x; o[1] = (__bf16)areg[i][0].y;
      o[2] = (__bf16)areg[i][0].z; o[3] = (__bf16)areg[i][0].w;
      o[4] = (__bf16)areg[i][1].x; o[5] = (__bf16)areg[i][1].y;
      o[6] = (__bf16)areg[i][1].z; o[7] = (__bf16)areg[i][1].w;
      *(bf16x8*)((char*)As[buf] + awoff[i]) = o;
    }
  };
  auto COMPUTE = [&](int buf) {
    #pragma unroll
    for (int kk = 0; kk < 2; ++kk) {
      bf16x8 af[4], bfv[4];
      #pragma unroll
      for (int m = 0; m < 4; ++m) {
        int r = wr * 64 + m * 16 + la;
        int off = (r * 128 + kk * 64 + lb * 16) ^ ((r & 7) << 4);
        af[m] = *(const bf16x8*)((const char*)As[buf] + off);
      }
      #pragma unroll
      for (int n = 0; n < 4; ++n) {
        int r = wcn * 64 + n * 16 + la;
        int off = (r * 128 + kk * 64 + lb * 16) ^ ((r & 7) << 4);
        bfv[n] = *(const bf16x8*)((const char*)Bs[buf] + off);
      }
      #pragma unroll
      for (int m = 0; m < 4; ++m)
        #pragma unroll
        for (int n = 0; n < 4; ++n)
          acc[m][n] = __builtin_amdgcn_mfma_f32_16x16x32_bf16(
              af[m], bfv[n], acc[m][n], 0, 0, 0);
    }
  };

  // prologue: fill buffer 0
  LOADA(0); DMAB(0, 0); WRITEA(0);
  __syncthreads();

  #pragma unroll 2
  for (int kt = 0; kt < 15; ++kt) {
    int cur = kt & 1;
    LOADA(kt + 1);          // A globals for t+1 (land during compute)
    DMAB(kt + 1, cur ^ 1);  // B DMA for t+1 (lands before end barrier)
    COMPUTE(cur);
    WRITEA(cur ^ 1);        // cvt + swizzled ds_write for t+1
    __syncthreads();        // drains vmcnt+lgkmcnt: buf cur^1 ready
  }
  COMPUTE(1);               // kt = 15

  // epilogue: tanh + w_score reduce over this block's 128 h columns
  const float* crow = c_ws + b * HID;
  float ch[4], wv4[4];
  #pragma unroll
  for (int n = 0; n < 4; ++n) {
    int h = n0 + wcn * 64 + n * 16 + la;
    ch[n] = crow[h];
    wv4[n] = wsc[h];
  }
  #pragma unroll
  for (int m = 0; m < 4; ++m) {
    #pragma unroll
    for (int j = 0; j < 4; ++j) {
      float rs = 0.f;
      #pragma unroll
      for (int n = 0; n < 4; ++n)
        rs += wv4[n] * tanhf(acc[m][n][j] + ch[n]);
      rs += __shfl_xor(rs, 1, 64);
      rs += __shfl_xor(rs, 2, 64);
      rs += __shfl_xor(rs, 4, 64);
      rs += __shfl_xor(rs, 8, 64);
      if (la == 0) {
        long grow = row0 + wr * 64 + m * 16 + lb * 4 + j;
        atomicAdd(scores + grow, rs);
      }
    }
  }
}

// ---------------------------------------------------------------------------
// softmax over s (in place). grid=32, block=256.
// ---------------------------------------------------------------------------
__global__ __launch_bounds__(256) void softmax_kernel(float* __restrict__ sc)
{
  int b = blockIdx.x, t = threadIdx.x;
  float* row = sc + (long)b * SEQ;
  float v[8]; float mx = -1e30f;
  #pragma unroll
  for (int j = 0; j < 8; ++j) { v[j] = row[t + j * 256]; mx = fmaxf(mx, v[j]); }
  #pragma unroll
  for (int m = 1; m < 64; m <<= 1) mx = fmaxf(mx, __shfl_xor(mx, m, 64));
  __shared__ float rmax[4], rsum[4];
  if ((t & 63) == 0) rmax[t >> 6] = mx;
  __syncthreads();
  mx = fmaxf(fmaxf(rmax[0], rmax[1]), fmaxf(rmax[2], rmax[3]));
  float s = 0.f;
  #pragma unroll
  for (int j = 0; j < 8; ++j) { v[j] = expf(v[j] - mx); s += v[j]; }
  #pragma unroll
  for (int m = 1; m < 64; m <<= 1) s += __shfl_xor(s, m, 64);
  if ((t & 63) == 0) rsum[t >> 6] = s;
  __syncthreads();
  float inv = 1.f / (rsum[0] + rsum[1] + rsum[2] + rsum[3]);
  #pragma unroll
  for (int j = 0; j < 8; ++j) row[t + j * 256] = v[j] * inv;
}

// ---------------------------------------------------------------------------
// attended stage 1: partial[b*64+sc][d] = sum_{s in 32-row chunk} attn*past
// grid = 32*64 = 2048 (8 blocks/CU), block = 256.
// ---------------------------------------------------------------------------
__global__ __launch_bounds__(256) void attend_partial(
    const float* __restrict__ past, const float* __restrict__ attn,
    float* __restrict__ partial)
{
  int blk = blockIdx.x;
  int b = blk >> 6, scn = blk & 63;
  int t = threadIdx.x;
  int s0 = scn * 32;
  __shared__ float aw[32];
  if (t < 32) aw[t] = attn[(long)b * SEQ + s0 + t];
  __syncthreads();
  const float4* pp = (const float4*)(past + ((long)(b * SEQ + s0)) * HID);
  float ax = 0.f, ay = 0.f, az = 0.f, awv = 0.f;
  #pragma unroll 4
  for (int s = 0; s < 32; ++s) {
    float wgt = aw[s];
    float4 v = pp[s * 256 + t];
    ax += wgt * v.x; ay += wgt * v.y; az += wgt * v.z; awv += wgt * v.w;
  }
  float4 o; o.x = ax; o.y = ay; o.z = az; o.w = awv;
  ((float4*)(partial + (long)blk * HID))[t] = o;
}

// attended stage 2: out[b,d] = sum_sc partial[b*64+sc][d]. grid=128, block=256.
__global__ __launch_bounds__(256) void attend_reduce(
    const float* __restrict__ partial, float* __restrict__ out)
{
  int blk = blockIdx.x;
  int b = blk >> 2, d = (blk & 3) * 256 + threadIdx.x;
  float s = 0.f;
  #pragma unroll
  for (int sc = 0; sc < 64; ++sc)
    s += partial[(long)(b * 64 + sc) * HID + d];
  out[(long)b * HID + d] = s;
}

// ---------------------------------------------------------------------------
extern "C" void kernel_launch(void* const* d_in, const int* in_sizes, int n_in,
                              void* d_out, int out_size, void* d_ws, size_t ws_size,
                              hipStream_t stream)
{
  const float* cur   = (const float*)d_in[0];  // (32,1024)
  const float* past  = (const float*)d_in[1];  // (32,2048,1024)
  const float* Wproj = (const float*)d_in[2];  // (1024,2048)
  const float* bproj = (const float*)d_in[3];  // (1024,)
  const float* wsc   = (const float*)d_in[4];  // (1024,)

  float* out      = (float*)d_out;
  float* attended = out;            // 32768 floats
  float* scores   = out + 32768;    // 65536 floats (scores -> attn in place)

  char* ws = (char*)d_ws;
  float*          c_ws    = (float*)ws;                              // 128 KB
  unsigned short* Bbf     = (unsigned short*)(ws + (128 << 10));     // 2 MB
  float*          partial = (float*)(ws + (128 << 10) + (2 << 20));  // 8 MB

  hipMemsetAsync(scores, 0, (size_t)BATCH * SEQ * sizeof(float), stream);
  prep_kernel<<<1024, 256, 0, stream>>>(cur, Wproj, bproj, Bbf, c_ws);
  score_gemm<<<4096, 256, 0, stream>>>(past, Bbf, c_ws, wsc, scores);
  softmax_kernel<<<BATCH, 256, 0, stream>>>(scores);
  attend_partial<<<32 * 64, 256, 0, stream>>>(past, scores, partial);
  attend_reduce<<<128, 256, 0, stream>>>(partial, attended);
}